// Round 8
// baseline (125.530 us; speedup 1.0000x reference)
//
#include <hip/hip_runtime.h>

// Modulated deformable conv2d, fp32 in/out, bf16 MFMA core.
// B=4, C=64, H=W=128, O=64, K=3x3, stride=1, pad=1, dil=1, og=1, groups=1.
//
// Round 8: software-pipeline the per-tap gather chain. Rounds 6/7 showed the
// kernel is NOT TLP-limited (2x waves -> same 50 us; VALUBusy 27%); the stall
// is the serial offset->addr->gather->bilinear->MFMA chain repeated 9x per
// wave. Two-stage pipeline, fully unrolled (static stage regs, no scratch):
//   iter k: load offsets(k+2) | addr+issue corner loads(k+1) | wait corners(k)
//           -> bilinear(k) -> 4 MFMA(k).
// Block/wave decomposition unchanged from round 7: 2048 blocks x 4 waves =
// (2 pixel-strips x 2 channel-halves); end-of-kernel LDS reduction.
// Fragment layouts (m89/m120-verified): A[m=lane&15][k=quad*8+j],
// B[k=quad*8+j][n=lane&15], D[row=quad*4+reg][col=lane&15].

#define BB 4
#define CC 64
#define HH 128
#define WW 128
#define OO 64
#define KHW 3
#define KK 9
#define HW (HH * WW)

typedef __bf16 bf16_t;
typedef bf16_t bf16x8 __attribute__((ext_vector_type(8)));
typedef float f32x4 __attribute__((ext_vector_type(4)));

// ---- x (NCHW fp32) -> xt (NHWC bf16), LDS-tiled transpose ----
__global__ __launch_bounds__(256) void nhwc_kernel(const float* __restrict__ x,
                                                   bf16_t* __restrict__ xt) {
    __shared__ float tile[64 * 65];
    const int t  = threadIdx.x;
    const int b  = blockIdx.x >> 8;
    const int p0 = (blockIdx.x & 255) << 6;
#pragma unroll
    for (int i = 0; i < 16; ++i) {
        int c = i * 4 + (t >> 6);
        int p = t & 63;
        tile[c * 65 + p] = x[(b * CC + c) * HW + p0 + p];  // coalesced read
    }
    __syncthreads();
#pragma unroll
    for (int i = 0; i < 16; ++i) {
        int p = i * 4 + (t >> 6);
        int c = t & 63;
        xt[(size_t)((b * HW) + p0 + p) * CC + c] = (bf16_t)tile[c * 65 + p];
    }
}

// ---- weight [O][C][3][3] fp32 -> B-fragment order bf16 ----
// wf element index: ((tap*2+q)*4+nt)*64*8 + lane*8 + j
//   holds W[o = nt*16 + (lane&15)][c = q*32 + (lane>>4)*8 + j][tap]
__global__ void wfrag_kernel(const float* __restrict__ w,
                             bf16_t* __restrict__ wf) {
    int i = blockIdx.x * blockDim.x + threadIdx.x;
    if (i >= OO * CC * KK) return;
    int j    = i & 7;
    int lane = (i >> 3) & 63;
    int nt   = (i >> 9) & 3;
    int q    = (i >> 11) & 1;
    int k    = i >> 12;
    int o = nt * 16 + (lane & 15);
    int c = q * 32 + ((lane >> 4) << 3) + j;
    wf[i] = (bf16_t)w[(o * CC + c) * KK + k];
}

__global__ __launch_bounds__(256, 4) void deform_conv_mfma(
    const bf16_t* __restrict__ xt, const float* __restrict__ offset,
    const float* __restrict__ mask, const bf16x8* __restrict__ wf,
    const float* __restrict__ bias, float* __restrict__ out) {
    const int t     = threadIdx.x;
    const int lane  = t & 63;
    const int wv    = t >> 6;
    const int strip = wv & 1;                  // which 16-pixel strip
    const int half  = wv >> 1;                 // which 32-channel half
    const int b     = blockIdx.x >> 9;         // 512 blocks per image
    const int p0    = (blockIdx.x & 511) << 5; // block's 32-pixel group
    const int m0    = strip << 4;
    const int col   = lane & 15;
    const int quad  = lane >> 4;

    const int rem = p0 + m0 + col;
    const int ho  = rem >> 7;
    const int wo  = rem & (WW - 1);
    const int cb  = (half << 5) + (quad << 3);

    const bf16_t* xb = xt + (size_t)b * HW * CC;

    __shared__ f32x4 red[2][4][64];            // [strip][nt][lane], 8 KB

    f32x4 acc[4];
#pragma unroll
    for (int nt = 0; nt < 4; ++nt) acc[nt] = (f32x4){0.f, 0.f, 0.f, 0.f};

    const int offbase = (b * (2 * KK)) * HW + rem;
    const int mbase   = (b * KK) * HW + rem;

    // addr+weight computation for tap k from its offsets
#define MK_TAP(k_, oy_, ox_, mm_, W0, W1, W2, W3, A0, A1, A2, A3)            \
    {                                                                        \
        float py = (oy_) + (float)((k_) / KHW) + (float)(ho - 1);            \
        float px = (ox_) + (float)((k_) % KHW) + (float)(wo - 1);            \
        float fy0 = floorf(py), fx0 = floorf(px);                            \
        float ly = py - fy0, lx = px - fx0;                                  \
        int y0 = (int)fy0, x0 = (int)fx0;                                    \
        int y1 = y0 + 1, x1 = x0 + 1;                                        \
        bool vy0 = (y0 >= 0) && (y0 < HH);                                   \
        bool vy1 = (y1 >= 0) && (y1 < HH);                                   \
        bool vx0 = (x0 >= 0) && (x0 < WW);                                   \
        bool vx1 = (x1 >= 0) && (x1 < WW);                                   \
        int cy0 = min(max(y0, 0), HH - 1), cy1 = min(max(y1, 0), HH - 1);    \
        int cx0 = min(max(x0, 0), WW - 1), cx1 = min(max(x1, 0), WW - 1);    \
        (W0) = (vy0 && vx0) ? (mm_) * (1.0f - ly) * (1.0f - lx) : 0.0f;      \
        (W1) = (vy0 && vx1) ? (mm_) * (1.0f - ly) * lx : 0.0f;               \
        (W2) = (vy1 && vx0) ? (mm_) * ly * (1.0f - lx) : 0.0f;               \
        (W3) = (vy1 && vx1) ? (mm_) * ly * lx : 0.0f;                        \
        (A0) = (cy0 * WW + cx0) * CC + cb;                                   \
        (A1) = (cy0 * WW + cx1) * CC + cb;                                   \
        (A2) = (cy1 * WW + cx0) * CC + cb;                                   \
        (A3) = (cy1 * WW + cx1) * CC + cb;                                   \
    }

    float ws0[2], ws1[2], ws2[2], ws3[2];      // stage weights
    bf16x8 cv0[2], cv1[2], cv2[2], cv3[2];     // stage corner vectors

    // Prologue: offsets for tap 0 and tap 1; issue tap 0's corner loads.
    float oyA = offset[offbase];
    float oxA = offset[offbase + HW];
    float mmA = mask[mbase];
    float oyB = offset[offbase + 2 * HW];
    float oxB = offset[offbase + 3 * HW];
    float mmB = mask[mbase + HW];
    {
        int a0, a1, a2, a3;
        MK_TAP(0, oyA, oxA, mmA, ws0[0], ws1[0], ws2[0], ws3[0], a0, a1, a2, a3);
        cv0[0] = *(const bf16x8*)(xb + a0);
        cv1[0] = *(const bf16x8*)(xb + a1);
        cv2[0] = *(const bf16x8*)(xb + a2);
        cv3[0] = *(const bf16x8*)(xb + a3);
    }

#pragma unroll
    for (int k = 0; k < KK; ++k) {
        const int s  = k & 1;
        const int sn = s ^ 1;

        // Stage A: load offsets for tap k+2 (a full iteration of slack).
        float oyN = 0.f, oxN = 0.f, mmN = 0.f;
        if (k + 2 < KK) {
            oyN = offset[offbase + (2 * k + 4) * HW];
            oxN = offset[offbase + (2 * k + 5) * HW];
            mmN = mask[mbase + (k + 2) * HW];
        }

        // Stage B: addr calc + issue corner loads for tap k+1.
        if (k + 1 < KK) {
            int a0, a1, a2, a3;
            MK_TAP(k + 1, oyB, oxB, mmB, ws0[sn], ws1[sn], ws2[sn], ws3[sn],
                   a0, a1, a2, a3);
            cv0[sn] = *(const bf16x8*)(xb + a0);
            cv1[sn] = *(const bf16x8*)(xb + a1);
            cv2[sn] = *(const bf16x8*)(xb + a2);
            cv3[sn] = *(const bf16x8*)(xb + a3);
        }

        // Stage C: consume tap k (waits only on its own corner loads).
        bf16x8 a0v = cv0[s], a1v = cv1[s], a2v = cv2[s], a3v = cv3[s];
        float w0 = ws0[s], w1 = ws1[s], w2 = ws2[s], w3 = ws3[s];
        bf16x8 af;
#pragma unroll
        for (int i = 0; i < 8; ++i) {
            float v = w0 * (float)a0v[i] + w1 * (float)a1v[i] +
                      w2 * (float)a2v[i] + w3 * (float)a3v[i];
            af[i] = (bf16_t)v;
        }

        const bf16x8* wk = wf + (size_t)((k * 2 + half) * 4) * 64;
#pragma unroll
        for (int nt = 0; nt < 4; ++nt) {
            bf16x8 bfr = wk[nt * 64 + lane];
            acc[nt] = __builtin_amdgcn_mfma_f32_16x16x32_bf16(af, bfr, acc[nt],
                                                              0, 0, 0);
        }

        // rotate offset registers
        oyB_rot: ;
        oyB = (k + 2 < KK) ? oyN : 0.f;
        oxB = (k + 2 < KK) ? oxN : 0.f;
        mmB = (k + 2 < KK) ? mmN : 0.f;
    }
#undef MK_TAP

    // ---- combine channel-halves, then epilogue from half==0 waves ----
    if (half == 1) {
#pragma unroll
        for (int nt = 0; nt < 4; ++nt) red[strip][nt][lane] = acc[nt];
    }
    __syncthreads();
    if (half == 0) {
#pragma unroll
        for (int nt = 0; nt < 4; ++nt) {
            int o = nt * 16 + col;
            float bv = bias[o];
            f32x4 r = acc[nt] + red[strip][nt][lane];
            r.x += bv; r.y += bv; r.z += bv; r.w += bv;
            // D[row=quad*4+reg][col]; row -> pixel, col -> output channel.
            float* dst = out + (size_t)(b * OO + o) * HW + p0 + m0 + quad * 4;
            *(f32x4*)dst = r;  // 4 consecutive pixels, 16B aligned
        }
    }
}

extern "C" void kernel_launch(void* const* d_in, const int* in_sizes, int n_in,
                              void* d_out, int out_size, void* d_ws,
                              size_t ws_size, hipStream_t stream) {
    const float* x      = (const float*)d_in[0];
    const float* offset = (const float*)d_in[1];
    const float* mask   = (const float*)d_in[2];
    const float* weight = (const float*)d_in[3];
    const float* bias   = (const float*)d_in[4];
    float* out = (float*)d_out;

    bf16_t* xt  = (bf16_t*)d_ws;                      // 4*16384*64*2 = 8 MB
    bf16_t* wfr = (bf16_t*)((char*)d_ws + (size_t)BB * HW * CC * 2);  // 72 KB

    nhwc_kernel<<<BB * (HW / 64), 256, 0, stream>>>(x, xt);

    int nw = OO * CC * KK;  // 36864
    wfrag_kernel<<<(nw + 255) / 256, 256, 0, stream>>>(weight, wfr);

    deform_conv_mfma<<<BB * (HW / 32), 256, 0, stream>>>(
        xt, offset, mask, (const bf16x8*)wfr, bias, out);
}